// Round 1
// baseline (570.271 us; speedup 1.0000x reference)
//
#include <hip/hip_runtime.h>

#define IN_F 8192
#define OUT_F 8192
#define NF4 (IN_F / 4)  // 2048 float4 per row

typedef float v4f __attribute__((ext_vector_type(4)));

// One WAVE per output row. No __syncthreads, no LDS, no register buffering of
// the trace row. Phase 1 streams the states row (nontemporal) into two scalar
// accumulators; a 64-lane butterfly gives every lane the exact integer totals,
// so every lane computes the spike identically. Phase 2 streams trace in,
// fuses decay+outer+clip, and streams the result out nontemporally. The x row
// (32 KB) is loaded with normal (cached) loads and is reused from L1/L2.
__global__ __launch_bounds__(256) void snn_fused_kernel(
    const float* __restrict__ x,       // [IN_F] spike_input
    const float* __restrict__ states,  // [OUT_F, IN_F]
    const float* __restrict__ mp,      // [OUT_F]
    const float* __restrict__ thr,     // [OUT_F]
    const float* __restrict__ trace,   // [OUT_F, IN_F]
    float* __restrict__ out)           // spikes[O] | v[O] | thr[O] | trace[O*I]
{
    const int wave = threadIdx.x >> 6;            // 4 waves per block
    const int lane = threadIdx.x & 63;
    const int o    = (blockIdx.x << 2) + wave;    // 2048 blocks * 4 rows

    // hoist tiny per-row scalars so they are in flight during phase 1
    const float mp_o  = mp[o];
    const float thr_o = thr[o];

    const v4f* __restrict__ x4 = (const v4f*)x;
    const v4f* __restrict__ s4 = (const v4f*)(states + (size_t)o * IN_F);

    // ---- Phase 1: ternary-weight row dot (states stream only) ----
    float wsum = 0.0f, dot = 0.0f;
#pragma unroll 8
    for (int k = 0; k < 32; ++k) {
        const int idx = lane + (k << 6);          // stride-64 f4: coalesced 4 KB/wave/step
        const v4f sv = __builtin_nontemporal_load(&s4[idx]);  // streaming
        const v4f xv = x4[idx];                               // cached
        const float w0 = (sv[0] > 50.0f) ? 1.0f : 0.0f;
        const float w1 = (sv[1] > 50.0f) ? 1.0f : 0.0f;
        const float w2 = (sv[2] > 50.0f) ? 1.0f : 0.0f;
        const float w3 = (sv[3] > 50.0f) ? 1.0f : 0.0f;
        wsum += (w0 + w1) + (w2 + w3);
        dot  += (w0 * xv[0] + w1 * xv[1]) + (w2 * xv[2] + w3 * xv[3]);
    }

    // 64-lane butterfly: every lane ends with the exact (integer-valued) totals
#pragma unroll
    for (int off = 1; off < 64; off <<= 1) {
        wsum += __shfl_xor(wsum, off);
        dot  += __shfl_xor(dot,  off);
    }

    const float conn    = fmaxf(wsum, 5.0f);
    const float current = dot * (15.0f / sqrtf(conn));
    const float v       = mp_o * 0.85f + current;
    const float spike   = (v >= thr_o) ? 1.0f : 0.0f;

    if (lane == 0) {
        out[o]             = spike;
        out[OUT_F + o]     = v * (1.0f - spike) * 0.1f;
        out[2 * OUT_F + o] = fminf(fmaxf(thr_o + (spike - 0.1f) * 0.1f, 2.0f), 15.0f);
    }

    // ---- Phase 2: trace decay + outer(spike, x), clamped; pure stream ----
    const v4f* __restrict__ tr4 = (const v4f*)(trace + (size_t)o * IN_F);
    v4f* __restrict__       ot4 = (v4f*)(out + 3 * OUT_F + (size_t)o * IN_F);
#pragma unroll 8
    for (int k = 0; k < 32; ++k) {
        const int idx = lane + (k << 6);
        const v4f tv = __builtin_nontemporal_load(&tr4[idx]);
        const v4f xv = x4[idx];
        v4f r;
        r[0] = fminf(fmaxf(tv[0] * 0.9f + spike * xv[0], 0.0f), 5.0f);
        r[1] = fminf(fmaxf(tv[1] * 0.9f + spike * xv[1], 0.0f), 5.0f);
        r[2] = fminf(fmaxf(tv[2] * 0.9f + spike * xv[2], 0.0f), 5.0f);
        r[3] = fminf(fmaxf(tv[3] * 0.9f + spike * xv[3], 0.0f), 5.0f);
        __builtin_nontemporal_store(r, &ot4[idx]);
    }
}

extern "C" void kernel_launch(void* const* d_in, const int* in_sizes, int n_in,
                              void* d_out, int out_size, void* d_ws, size_t ws_size,
                              hipStream_t stream) {
    const float* x      = (const float*)d_in[0];  // spike_input [8192]
    const float* states = (const float*)d_in[1];  // synapse_states [8192*8192]
    const float* mp     = (const float*)d_in[2];  // membrane_potential [8192]
    const float* thr    = (const float*)d_in[3];  // adaptive_threshold [8192]
    const float* trace  = (const float*)d_in[4];  // eligibility_trace [8192*8192]
    float* out = (float*)d_out;

    snn_fused_kernel<<<OUT_F / 4, 256, 0, stream>>>(x, states, mp, thr, trace, out);
}

// Round 2
// 567.101 us; speedup vs baseline: 1.0056x; 1.0056x over previous
//
#include <hip/hip_runtime.h>

#define IN_F 8192
#define OUT_F 8192

typedef float v4f __attribute__((ext_vector_type(4)));

// ---------------- Kernel A: spike computation (pure read stream) ----------
// One block per output row. Streams the 32 KB states row (nontemporal),
// ternary-weight dot with cached x, wave shuffle-reduce + LDS combine,
// thread 0 writes the 3 per-row scalars. No bulk stores gated behind the
// reduction -- the barrier only guards 3 scalar writes.
__global__ __launch_bounds__(256) void spike_kernel(
    const float* __restrict__ x,       // [IN_F]
    const float* __restrict__ states,  // [OUT_F, IN_F]
    const float* __restrict__ mp,      // [OUT_F]
    const float* __restrict__ thr,     // [OUT_F]
    float* __restrict__ out)           // spikes[O] | v[O] | thr[O] | ...
{
    const int o = blockIdx.x;
    const int t = threadIdx.x;

    __shared__ float red_ws[4];
    __shared__ float red_dot[4];

    const float mp_o  = mp[o];
    const float thr_o = thr[o];

    const v4f* __restrict__ x4 = (const v4f*)x;
    const v4f* __restrict__ s4 = (const v4f*)(states + (size_t)o * IN_F);

    float wsum = 0.0f, dot = 0.0f;
#pragma unroll
    for (int k = 0; k < 8; ++k) {
        const int idx = t + (k << 8);
        const v4f sv = __builtin_nontemporal_load(&s4[idx]);  // streaming
        const v4f xv = x4[idx];                               // cached
        const float w0 = (sv[0] > 50.0f) ? 1.0f : 0.0f;
        const float w1 = (sv[1] > 50.0f) ? 1.0f : 0.0f;
        const float w2 = (sv[2] > 50.0f) ? 1.0f : 0.0f;
        const float w3 = (sv[3] > 50.0f) ? 1.0f : 0.0f;
        wsum += (w0 + w1) + (w2 + w3);
        dot  += (w0 * xv[0] + w1 * xv[1]) + (w2 * xv[2] + w3 * xv[3]);
    }

#pragma unroll
    for (int off = 32; off > 0; off >>= 1) {
        wsum += __shfl_down(wsum, off);
        dot  += __shfl_down(dot,  off);
    }
    const int wave = t >> 6;
    if ((t & 63) == 0) { red_ws[wave] = wsum; red_dot[wave] = dot; }
    __syncthreads();

    if (t == 0) {
        // sums are exact small integers in f32 -> order-independent, bit-exact
        const float ws = (red_ws[0] + red_ws[1]) + (red_ws[2] + red_ws[3]);
        const float dt = (red_dot[0] + red_dot[1]) + (red_dot[2] + red_dot[3]);
        const float conn    = fmaxf(ws, 5.0f);
        const float current = dt * (15.0f / sqrtf(conn));
        const float v       = mp_o * 0.85f + current;
        const float spike   = (v >= thr_o) ? 1.0f : 0.0f;
        out[o]             = spike;
        out[OUT_F + o]     = v * (1.0f - spike) * 0.1f;
        out[2 * OUT_F + o] = fminf(fmaxf(thr_o + (spike - 0.1f) * 0.1f, 2.0f), 15.0f);
    }
}

// ---------------- Kernel B: trace update (pure copy-transform stream) -----
// Flat grid-stride over all 16.7M float4s. Reads trace (NT), spike (L2-hot
// scalar broadcast: all 64 lanes of a wave are in the same row), x (L2-hot),
// writes updated trace (NT). No barriers, no reductions, tiny VGPR count.
__global__ __launch_bounds__(256) void trace_kernel(
    const float* __restrict__ x,       // [IN_F]
    const float* __restrict__ trace,   // [OUT_F, IN_F]
    const float* __restrict__ spikes,  // out[0..OUT_F) written by kernel A
    float* __restrict__ otrace)        // out + 3*OUT_F
{
    const int tid = blockIdx.x * 256 + threadIdx.x;
    const v4f* __restrict__ x4  = (const v4f*)x;
    const v4f* __restrict__ tr4 = (const v4f*)trace;
    v4f* __restrict__       ot4 = (v4f*)otrace;

#pragma unroll
    for (int k = 0; k < 8; ++k) {
        const int idx = tid + k * (8192 * 256);     // 2,097,152-f4 stride
        const int row = idx >> 11;                  // 2048 f4 per row
        const float s = spikes[row];                // wave-uniform L2 hit
        const v4f tv = __builtin_nontemporal_load(&tr4[idx]);
        const v4f xv = x4[idx & 2047];
        v4f r;
        r[0] = fminf(fmaxf(tv[0] * 0.9f + s * xv[0], 0.0f), 5.0f);
        r[1] = fminf(fmaxf(tv[1] * 0.9f + s * xv[1], 0.0f), 5.0f);
        r[2] = fminf(fmaxf(tv[2] * 0.9f + s * xv[2], 0.0f), 5.0f);
        r[3] = fminf(fmaxf(tv[3] * 0.9f + s * xv[3], 0.0f), 5.0f);
        __builtin_nontemporal_store(r, &ot4[idx]);
    }
}

extern "C" void kernel_launch(void* const* d_in, const int* in_sizes, int n_in,
                              void* d_out, int out_size, void* d_ws, size_t ws_size,
                              hipStream_t stream) {
    const float* x      = (const float*)d_in[0];  // spike_input [8192]
    const float* states = (const float*)d_in[1];  // synapse_states [8192*8192]
    const float* mp     = (const float*)d_in[2];  // membrane_potential [8192]
    const float* thr    = (const float*)d_in[3];  // adaptive_threshold [8192]
    const float* trace  = (const float*)d_in[4];  // eligibility_trace [8192*8192]
    float* out = (float*)d_out;

    spike_kernel<<<OUT_F, 256, 0, stream>>>(x, states, mp, thr, out);
    // stream-ordered: trace_kernel sees kernel A's spikes
    trace_kernel<<<8192, 256, 0, stream>>>(x, trace, out, out + 3 * OUT_F);
}

// Round 3
// 561.295 us; speedup vs baseline: 1.0160x; 1.0103x over previous
//
#include <hip/hip_runtime.h>

#define IN_F 8192
#define OUT_F 8192

typedef float v4f __attribute__((ext_vector_type(4)));

// One block per output row, single barrier. Best-measured structure
// (559.6 / 560.5 us across two sessions). All row loads (x, states, trace)
// issue up front for max memory-level parallelism; spike computed
// redundantly by every thread from LDS partials; trace update stored
// nontemporally. Back-solved kernel time ~125 us == the 805 MB mandatory
// traffic at the ~6.5 TB/s this arena demonstrably sustains -> memory
// roofline; wave-per-row (+9.8 us) and two-kernel split (+6.6 us) both
// regressed against this.
__global__ __launch_bounds__(256) void snn_fused_kernel(
    const float* __restrict__ x,       // [IN_F] spike_input
    const float* __restrict__ states,  // [OUT_F, IN_F]
    const float* __restrict__ mp,      // [OUT_F]
    const float* __restrict__ thr,     // [OUT_F]
    const float* __restrict__ trace,   // [OUT_F, IN_F]
    float* __restrict__ out)           // spikes[O] | v[O] | thr[O] | trace[O*I]
{
    const int o = blockIdx.x;
    const int t = threadIdx.x;

    __shared__ float red_ws[4];
    __shared__ float red_dot[4];

    // hoist tiny per-row scalars off the post-barrier critical path
    const float mp_o  = mp[o];
    const float thr_o = thr[o];

    const v4f* __restrict__ x4  = (const v4f*)x;
    const v4f* __restrict__ s4  = (const v4f*)(states + (size_t)o * IN_F);
    const v4f* __restrict__ tr4 = (const v4f*)(trace  + (size_t)o * IN_F);

    // 2048 float4 per row; 256 threads -> 8 float4 each (strided)
    v4f xr[8], tr[8];
    float wsum = 0.0f, dot = 0.0f;
#pragma unroll
    for (int k = 0; k < 8; ++k) {
        const int idx = t + (k << 8);
        xr[k] = x4[idx];                                    // cached (reused by all rows)
        tr[k] = __builtin_nontemporal_load(&tr4[idx]);      // streaming
        const v4f sv = __builtin_nontemporal_load(&s4[idx]); // streaming
        const float w0 = (sv[0] > 50.0f) ? 1.0f : 0.0f;
        const float w1 = (sv[1] > 50.0f) ? 1.0f : 0.0f;
        const float w2 = (sv[2] > 50.0f) ? 1.0f : 0.0f;
        const float w3 = (sv[3] > 50.0f) ? 1.0f : 0.0f;
        wsum += (w0 + w1) + (w2 + w3);
        dot  += (w0 * xr[k][0] + w1 * xr[k][1]) + (w2 * xr[k][2] + w3 * xr[k][3]);
    }

    // 64-lane wave reduce
#pragma unroll
    for (int off = 32; off > 0; off >>= 1) {
        wsum += __shfl_down(wsum, off);
        dot  += __shfl_down(dot,  off);
    }
    const int wave = t >> 6;
    if ((t & 63) == 0) { red_ws[wave] = wsum; red_dot[wave] = dot; }
    __syncthreads();

    // every thread computes spike redundantly (values are exact integers in f32,
    // so all orders agree and match the numpy reference bit-wise for the compare)
    const float ws = (red_ws[0] + red_ws[1]) + (red_ws[2] + red_ws[3]);
    const float dt = (red_dot[0] + red_dot[1]) + (red_dot[2] + red_dot[3]);
    const float conn    = fmaxf(ws, 5.0f);
    const float current = dt * (15.0f / sqrtf(conn));
    const float v       = mp_o * 0.85f + current;
    const float spike   = (v >= thr_o) ? 1.0f : 0.0f;

    if (t == 0) {
        out[o]             = spike;
        out[OUT_F + o]     = v * (1.0f - spike) * 0.1f;
        out[2 * OUT_F + o] = fminf(fmaxf(thr_o + (spike - 0.1f) * 0.1f, 2.0f), 15.0f);
    }

    v4f* __restrict__ ot4 = (v4f*)(out + 3 * OUT_F + (size_t)o * IN_F);
#pragma unroll
    for (int k = 0; k < 8; ++k) {
        const int idx = t + (k << 8);
        v4f r;
        r[0] = fminf(fmaxf(tr[k][0] * 0.9f + spike * xr[k][0], 0.0f), 5.0f);
        r[1] = fminf(fmaxf(tr[k][1] * 0.9f + spike * xr[k][1], 0.0f), 5.0f);
        r[2] = fminf(fmaxf(tr[k][2] * 0.9f + spike * xr[k][2], 0.0f), 5.0f);
        r[3] = fminf(fmaxf(tr[k][3] * 0.9f + spike * xr[k][3], 0.0f), 5.0f);
        __builtin_nontemporal_store(r, &ot4[idx]);
    }
}

extern "C" void kernel_launch(void* const* d_in, const int* in_sizes, int n_in,
                              void* d_out, int out_size, void* d_ws, size_t ws_size,
                              hipStream_t stream) {
    const float* x      = (const float*)d_in[0];  // spike_input [8192]
    const float* states = (const float*)d_in[1];  // synapse_states [8192*8192]
    const float* mp     = (const float*)d_in[2];  // membrane_potential [8192]
    const float* thr    = (const float*)d_in[3];  // adaptive_threshold [8192]
    const float* trace  = (const float*)d_in[4];  // eligibility_trace [8192*8192]
    float* out = (float*)d_out;

    snn_fused_kernel<<<OUT_F, 256, 0, stream>>>(x, states, mp, thr, trace, out);
}